// Round 3
// baseline (500.836 us; speedup 1.0000x reference)
//
#include <hip/hip_runtime.h>
#include <hip/hip_bf16.h>
#include <cstdint>
#include <cstddef>

// Problem constants (T,B,D,H,L = 1024,64,512,512,2)
#define T_DIM 1024
#define B_DIM 64
#define D_DIM 512
#define H_DIM 512
#define TBROWS (T_DIM * B_DIM)           // 65536 GEMM rows
#define BH (B_DIM * H_DIM)               // 32768
#define TBH ((size_t)T_DIM * (size_t)BH) // 33554432 elements

typedef __bf16 bf16x8 __attribute__((ext_vector_type(8)));
typedef float floatx4 __attribute__((ext_vector_type(4)));

// ---------------------------------------------------------------------------
// async global->LDS, 16B per lane. LDS dest is wave-uniform base + lane*16.
// ---------------------------------------------------------------------------
__device__ __forceinline__ void async_load16(const void* g, void* l) {
  __builtin_amdgcn_global_load_lds(
      (const __attribute__((address_space(1))) unsigned int*)g,
      (__attribute__((address_space(3))) unsigned int*)l,
      16, 0, 0);
}

// ---------------------------------------------------------------------------
// Streaming f32 -> bf16 (x, 128 MB read / 64 MB write, HBM-rate)
// ---------------------------------------------------------------------------
__global__ __launch_bounds__(256) void cvt_bf16_kernel(
    const float* __restrict__ in, __bf16* __restrict__ out, long n) {
  long i = ((long)blockIdx.x * 256 + threadIdx.x) * 8;
  if (i + 8 <= n) {
    const float4 a = *(const float4*)(in + i);
    const float4 b = *(const float4*)(in + i + 4);
    bf16x8 v;
    v[0] = (__bf16)a.x; v[1] = (__bf16)a.y; v[2] = (__bf16)a.z; v[3] = (__bf16)a.w;
    v[4] = (__bf16)b.x; v[5] = (__bf16)b.y; v[6] = (__bf16)b.z; v[7] = (__bf16)b.w;
    *(bf16x8*)(out + i) = v;
  }
}

// ---------------------------------------------------------------------------
// Merged prep: blocks [0,1024): Wc[h,d] = sum_e w0[h,e]*fc_w[e,d] (bf16)
//              blocks [1024,1152): w1 -> bf16 (2048 elems/block)
//              blocks [1152,1154): bcomb[h] = b0[h] + sum_e w0[h,e]*fc_b[e]
// ---------------------------------------------------------------------------
__global__ __launch_bounds__(256) void prep_kernel(
    const float* __restrict__ w0, const float* __restrict__ fc_w,
    const float* __restrict__ fc_b, const float* __restrict__ b0,
    const float* __restrict__ w1, __bf16* __restrict__ Wc,
    __bf16* __restrict__ w1bf, float* __restrict__ bcomb) {
  const int blk = blockIdx.x;
  if (blk < 1024) {
    const int h = blk >> 1;
    const int d = ((blk & 1) << 8) + threadIdx.x;
    float a0 = 0.f, a1 = 0.f, a2 = 0.f, a3 = 0.f;
    for (int e = 0; e < D_DIM; e += 4) {
      a0 = fmaf(w0[h * D_DIM + e + 0], fc_w[(size_t)(e + 0) * D_DIM + d], a0);
      a1 = fmaf(w0[h * D_DIM + e + 1], fc_w[(size_t)(e + 1) * D_DIM + d], a1);
      a2 = fmaf(w0[h * D_DIM + e + 2], fc_w[(size_t)(e + 2) * D_DIM + d], a2);
      a3 = fmaf(w0[h * D_DIM + e + 3], fc_w[(size_t)(e + 3) * D_DIM + d], a3);
    }
    Wc[(size_t)h * D_DIM + d] = (__bf16)((a0 + a1) + (a2 + a3));
  } else if (blk < 1152) {
    const long i = ((long)(blk - 1024) * 256 + threadIdx.x) * 8;
    const float4 a = *(const float4*)(w1 + i);
    const float4 b = *(const float4*)(w1 + i + 4);
    bf16x8 v;
    v[0] = (__bf16)a.x; v[1] = (__bf16)a.y; v[2] = (__bf16)a.z; v[3] = (__bf16)a.w;
    v[4] = (__bf16)b.x; v[5] = (__bf16)b.y; v[6] = (__bf16)b.z; v[7] = (__bf16)b.w;
    *(bf16x8*)(w1bf + i) = v;
  } else {
    const int h = (blk - 1152) * 256 + threadIdx.x;
    float acc = b0[h];
    for (int e = 0; e < D_DIM; ++e)
      acc = fmaf(w0[(size_t)h * D_DIM + e], fc_b[e], acc);
    bcomb[h] = acc;
  }
}

// ---------------------------------------------------------------------------
// NT bf16 GEMM (m97 structure): C[m,n] = sum_k A[m,k]*Bm[n,k] + bias[n],
// bf16 output. 128x128 tile, BK=32, 4 waves 2x2, 16x16x32 MFMA,
// global_load_lds width 16.
// ---------------------------------------------------------------------------
#define BM 128
#define BN 128
#define BK 32

__global__ __launch_bounds__(256) void gemm_bt_bias(
    const __bf16* __restrict__ A,   // [M,K]
    const __bf16* __restrict__ Bm,  // [N,K]
    const float* __restrict__ bias, // [N]
    __bf16* __restrict__ C,         // [M,N]
    int M, int N, int K) {
  __shared__ __bf16 As[BM * BK];
  __shared__ __bf16 Bs[BN * BK];

  const int tid = threadIdx.x;
  const int lane = tid & 63;
  const int wave = tid >> 6;
  const int nb = N / BN;
  const int bm = blockIdx.x / nb;
  const int bn = blockIdx.x % nb;
  const int m0 = bm * BM, n0 = bn * BN;

  floatx4 zero = {0.f, 0.f, 0.f, 0.f};
  floatx4 acc[4][4];
#pragma unroll
  for (int i = 0; i < 4; i++)
#pragma unroll
    for (int j = 0; j < 4; j++) acc[i][j] = zero;

  const int e0 = (wave * 2 + 0) * 64 + lane;
  const int e1 = (wave * 2 + 1) * 64 + lane;
  const int r0 = e0 >> 2, c0 = (e0 & 3) * 8;
  const int r1 = e1 >> 2, c1 = (e1 & 3) * 8;

  const int tm = (wave >> 1) * 64;
  const int tn = (wave & 1) * 64;
  const int lrow = lane & 15;
  const int lk = (lane >> 4) * 8;

  for (int k0 = 0; k0 < K; k0 += BK) {
    async_load16(&A[(size_t)(m0 + r0) * K + k0 + c0], &As[(wave * 2 + 0) * 512]);
    async_load16(&A[(size_t)(m0 + r1) * K + k0 + c1], &As[(wave * 2 + 1) * 512]);
    async_load16(&Bm[(size_t)(n0 + r0) * K + k0 + c0], &Bs[(wave * 2 + 0) * 512]);
    async_load16(&Bm[(size_t)(n0 + r1) * K + k0 + c1], &Bs[(wave * 2 + 1) * 512]);
    __syncthreads();

    bf16x8 af[4], bfr[4];
#pragma unroll
    for (int i = 0; i < 4; i++) {
      af[i]  = *(const bf16x8*)&As[(tm + i * 16 + lrow) * BK + lk];
      bfr[i] = *(const bf16x8*)&Bs[(tn + i * 16 + lrow) * BK + lk];
    }
#pragma unroll
    for (int i = 0; i < 4; i++)
#pragma unroll
      for (int j = 0; j < 4; j++)
        acc[i][j] = __builtin_amdgcn_mfma_f32_16x16x32_bf16(af[i], bfr[j],
                                                            acc[i][j], 0, 0, 0);
    __syncthreads();
  }

  // Epilogue: C/D layout col = lane&15, row = (lane>>4)*4 + reg; bf16 out
  const int ccol = lane & 15;
  const int crow = (lane >> 4) * 4;
  float bv[4];
#pragma unroll
  for (int j = 0; j < 4; j++) bv[j] = bias[n0 + tn + j * 16 + ccol];
#pragma unroll
  for (int i = 0; i < 4; i++) {
#pragma unroll
    for (int j = 0; j < 4; j++) {
      const size_t base =
          (size_t)(m0 + tm + i * 16 + crow) * N + (n0 + tn + j * 16 + ccol);
#pragma unroll
      for (int r = 0; r < 4; r++)
        C[base + (size_t)r * N] = (__bf16)(acc[i][j][r] + bv[j]);
    }
  }
}

// ---------------------------------------------------------------------------
// IndRNN scan: one thread per (b,h); pre is bf16. Only 2 waves/CU are
// possible (32768 chains), so latency hiding is pure ILP: prefetch depth 64
// keeps 64 loads (128 B/lane, 16 KB/CU) in flight across chunk boundaries.
// ---------------------------------------------------------------------------
template <bool BF16OUT>
__global__ __launch_bounds__(64) void scan_kernel(
    const __bf16* __restrict__ pre, // [T, BH] bf16
    const float* __restrict__ h0,   // [BH]
    const float* __restrict__ u,    // [H]
    void* __restrict__ outp,        // [T, BH] bf16 or f32
    float* __restrict__ hn) {       // [BH]
  const int idx = blockIdx.x * 64 + threadIdx.x;
  const float uu = u[idx & (H_DIM - 1)];
  float h = h0[idx];
  __bf16* __restrict__ ob = (__bf16*)outp;
  float* __restrict__ of = (float*)outp;

  float v[64];
#pragma unroll
  for (int s = 0; s < 64; s++) v[s] = (float)pre[(size_t)s * BH + idx];

  for (int t0 = 0; t0 < T_DIM; t0 += 64) {
    float w[64];
    const bool more = (t0 + 64) < T_DIM;
    if (more) {
#pragma unroll
      for (int s = 0; s < 64; s++)
        w[s] = (float)pre[(size_t)(t0 + 64 + s) * BH + idx];
    }
#pragma unroll
    for (int s = 0; s < 64; s++) {
      h = fmaxf(fmaf(uu, h, v[s]), 0.0f);
      if (BF16OUT)
        ob[(size_t)(t0 + s) * BH + idx] = (__bf16)h;
      else
        of[(size_t)(t0 + s) * BH + idx] = h;
    }
    if (more) {
#pragma unroll
      for (int s = 0; s < 64; s++) v[s] = w[s];
    }
  }
  hn[idx] = h;
}

// ---------------------------------------------------------------------------
extern "C" void kernel_launch(void* const* d_in, const int* in_sizes, int n_in,
                              void* d_out, int out_size, void* d_ws,
                              size_t ws_size, hipStream_t stream) {
  (void)in_sizes; (void)n_in; (void)out_size; (void)ws_size;
  const float* x      = (const float*)d_in[0]; // [T,B,D]
  const float* hidden = (const float*)d_in[1]; // [L,B,H]
  const float* fc_w   = (const float*)d_in[2]; // [D,D]
  const float* fc_b   = (const float*)d_in[3]; // [D]
  const float* w0     = (const float*)d_in[4]; // [H,D]
  const float* b0     = (const float*)d_in[5]; // [H]
  const float* u0     = (const float*)d_in[6]; // [H]
  const float* w1     = (const float*)d_in[7]; // [H,H]
  const float* b1     = (const float*)d_in[8]; // [H]
  const float* u1     = (const float*)d_in[9]; // [H]
  float* out = (float*)d_out;

  // workspace (~192 MB): xbf / pre / out0 (bf16, 64 MB each) + small weights
  char* ws = (char*)d_ws;
  __bf16* xbf  = (__bf16*)ws;                   // 64 MB
  __bf16* pre  = (__bf16*)(ws + TBH * 2);       // 64 MB (pre0, then pre1)
  __bf16* out0 = (__bf16*)(ws + 2 * TBH * 2);   // 64 MB
  char*   tail = ws + 3 * TBH * 2;
  __bf16* Wc    = (__bf16*)tail;                // 512 KB
  __bf16* w1bf  = (__bf16*)(tail + 512 * 1024); // 512 KB
  float*  bcomb = (float*)(tail + 1024 * 1024); // 2 KB

  float* hn = out + TBH; // [2, BH] after out1

  // 1) prep: Wc = w0@fc_w (bf16), w1->bf16, bcomb = b0 + w0@fc_b
  prep_kernel<<<1154, 256, 0, stream>>>(w0, fc_w, fc_b, b0, w1, Wc, w1bf, bcomb);
  // 2) x -> bf16 (streaming, reads x exactly once)
  cvt_bf16_kernel<<<(int)(TBH / (256 * 8)), 256, 0, stream>>>(x, xbf, (long)TBH);
  // 3) pre0 = xbf @ Wc^T + bcomb -> bf16
  gemm_bt_bias<<<(TBROWS / BM) * (H_DIM / BN), 256, 0, stream>>>(
      xbf, Wc, bcomb, pre, TBROWS, H_DIM, D_DIM);
  // 4) layer-0 scan: out0 (bf16), hn[0]
  scan_kernel<true><<<BH / 64, 64, 0, stream>>>(pre, hidden, u0, (void*)out0, hn);
  // 5) pre1 = out0 @ w1^T + b1 -> bf16 (reuse pre buffer)
  gemm_bt_bias<<<(TBROWS / BM) * (H_DIM / BN), 256, 0, stream>>>(
      out0, w1bf, b1, pre, TBROWS, H_DIM, H_DIM);
  // 6) layer-1 scan: out1 (f32) -> d_out, hn[1]
  scan_kernel<false><<<BH / 64, 64, 0, stream>>>(pre, hidden + BH, u1,
                                                 (void*)out, hn + BH);
}

// Round 4
// 453.083 us; speedup vs baseline: 1.1054x; 1.1054x over previous
//
#include <hip/hip_runtime.h>
#include <hip/hip_bf16.h>
#include <cstdint>
#include <cstddef>

// Problem constants (T,B,D,H,L = 1024,64,512,512,2)
#define T_DIM 1024
#define B_DIM 64
#define D_DIM 512
#define H_DIM 512
#define TBROWS (T_DIM * B_DIM)           // 65536 GEMM rows
#define BH (B_DIM * H_DIM)               // 32768
#define TBH ((size_t)T_DIM * (size_t)BH) // 33554432 elements

typedef __bf16 bf16x8 __attribute__((ext_vector_type(8)));
typedef float floatx4 __attribute__((ext_vector_type(4)));

// ---------------------------------------------------------------------------
// async global->LDS, 16B per lane. LDS dest is wave-uniform base + lane*16.
// ---------------------------------------------------------------------------
__device__ __forceinline__ void async_load16(const void* g, void* l) {
  __builtin_amdgcn_global_load_lds(
      (const __attribute__((address_space(1))) unsigned int*)g,
      (__attribute__((address_space(3))) unsigned int*)l,
      16, 0, 0);
}

// ---------------------------------------------------------------------------
// Streaming f32 -> bf16 (x, 128 MB read / 64 MB write, HBM-rate)
// ---------------------------------------------------------------------------
__global__ __launch_bounds__(256) void cvt_bf16_kernel(
    const float* __restrict__ in, __bf16* __restrict__ out, long n) {
  long i = ((long)blockIdx.x * 256 + threadIdx.x) * 8;
  if (i + 8 <= n) {
    const float4 a = *(const float4*)(in + i);
    const float4 b = *(const float4*)(in + i + 4);
    bf16x8 v;
    v[0] = (__bf16)a.x; v[1] = (__bf16)a.y; v[2] = (__bf16)a.z; v[3] = (__bf16)a.w;
    v[4] = (__bf16)b.x; v[5] = (__bf16)b.y; v[6] = (__bf16)b.z; v[7] = (__bf16)b.w;
    *(bf16x8*)(out + i) = v;
  }
}

// ---------------------------------------------------------------------------
// Merged prep: blocks [0,1024): Wc[h,d] = sum_e w0[h,e]*fc_w[e,d] (bf16)
//              blocks [1024,1152): w1 -> bf16 (2048 elems/block)
//              blocks [1152,1154): bcomb[h] = b0[h] + sum_e w0[h,e]*fc_b[e]
// ---------------------------------------------------------------------------
__global__ __launch_bounds__(256) void prep_kernel(
    const float* __restrict__ w0, const float* __restrict__ fc_w,
    const float* __restrict__ fc_b, const float* __restrict__ b0,
    const float* __restrict__ w1, __bf16* __restrict__ Wc,
    __bf16* __restrict__ w1bf, float* __restrict__ bcomb) {
  const int blk = blockIdx.x;
  if (blk < 1024) {
    const int h = blk >> 1;
    const int d = ((blk & 1) << 8) + threadIdx.x;
    float a0 = 0.f, a1 = 0.f, a2 = 0.f, a3 = 0.f;
    for (int e = 0; e < D_DIM; e += 4) {
      a0 = fmaf(w0[h * D_DIM + e + 0], fc_w[(size_t)(e + 0) * D_DIM + d], a0);
      a1 = fmaf(w0[h * D_DIM + e + 1], fc_w[(size_t)(e + 1) * D_DIM + d], a1);
      a2 = fmaf(w0[h * D_DIM + e + 2], fc_w[(size_t)(e + 2) * D_DIM + d], a2);
      a3 = fmaf(w0[h * D_DIM + e + 3], fc_w[(size_t)(e + 3) * D_DIM + d], a3);
    }
    Wc[(size_t)h * D_DIM + d] = (__bf16)((a0 + a1) + (a2 + a3));
  } else if (blk < 1152) {
    const long i = ((long)(blk - 1024) * 256 + threadIdx.x) * 8;
    const float4 a = *(const float4*)(w1 + i);
    const float4 b = *(const float4*)(w1 + i + 4);
    bf16x8 v;
    v[0] = (__bf16)a.x; v[1] = (__bf16)a.y; v[2] = (__bf16)a.z; v[3] = (__bf16)a.w;
    v[4] = (__bf16)b.x; v[5] = (__bf16)b.y; v[6] = (__bf16)b.z; v[7] = (__bf16)b.w;
    *(bf16x8*)(w1bf + i) = v;
  } else {
    const int h = (blk - 1152) * 256 + threadIdx.x;
    float acc = b0[h];
    for (int e = 0; e < D_DIM; ++e)
      acc = fmaf(w0[(size_t)h * D_DIM + e], fc_b[e], acc);
    bcomb[h] = acc;
  }
}

// ---------------------------------------------------------------------------
// NT bf16 GEMM (m97 structure): C[m,n] = sum_k A[m,k]*Bm[n,k] + bias[n],
// bf16 output. 128x128 tile, BK=32, 4 waves 2x2, 16x16x32 MFMA,
// global_load_lds width 16.
// ---------------------------------------------------------------------------
#define BM 128
#define BN 128
#define BK 32

__global__ __launch_bounds__(256) void gemm_bt_bias(
    const __bf16* __restrict__ A,   // [M,K]
    const __bf16* __restrict__ Bm,  // [N,K]
    const float* __restrict__ bias, // [N]
    __bf16* __restrict__ C,         // [M,N]
    int M, int N, int K) {
  __shared__ __bf16 As[BM * BK];
  __shared__ __bf16 Bs[BN * BK];

  const int tid = threadIdx.x;
  const int lane = tid & 63;
  const int wave = tid >> 6;
  const int nb = N / BN;
  const int bm = blockIdx.x / nb;
  const int bn = blockIdx.x % nb;
  const int m0 = bm * BM, n0 = bn * BN;

  floatx4 zero = {0.f, 0.f, 0.f, 0.f};
  floatx4 acc[4][4];
#pragma unroll
  for (int i = 0; i < 4; i++)
#pragma unroll
    for (int j = 0; j < 4; j++) acc[i][j] = zero;

  const int e0 = (wave * 2 + 0) * 64 + lane;
  const int e1 = (wave * 2 + 1) * 64 + lane;
  const int r0 = e0 >> 2, c0 = (e0 & 3) * 8;
  const int r1 = e1 >> 2, c1 = (e1 & 3) * 8;

  const int tm = (wave >> 1) * 64;
  const int tn = (wave & 1) * 64;
  const int lrow = lane & 15;
  const int lk = (lane >> 4) * 8;

  for (int k0 = 0; k0 < K; k0 += BK) {
    async_load16(&A[(size_t)(m0 + r0) * K + k0 + c0], &As[(wave * 2 + 0) * 512]);
    async_load16(&A[(size_t)(m0 + r1) * K + k0 + c1], &As[(wave * 2 + 1) * 512]);
    async_load16(&Bm[(size_t)(n0 + r0) * K + k0 + c0], &Bs[(wave * 2 + 0) * 512]);
    async_load16(&Bm[(size_t)(n0 + r1) * K + k0 + c1], &Bs[(wave * 2 + 1) * 512]);
    __syncthreads();

    bf16x8 af[4], bfr[4];
#pragma unroll
    for (int i = 0; i < 4; i++) {
      af[i]  = *(const bf16x8*)&As[(tm + i * 16 + lrow) * BK + lk];
      bfr[i] = *(const bf16x8*)&Bs[(tn + i * 16 + lrow) * BK + lk];
    }
#pragma unroll
    for (int i = 0; i < 4; i++)
#pragma unroll
      for (int j = 0; j < 4; j++)
        acc[i][j] = __builtin_amdgcn_mfma_f32_16x16x32_bf16(af[i], bfr[j],
                                                            acc[i][j], 0, 0, 0);
    __syncthreads();
  }

  // Epilogue: C/D layout col = lane&15, row = (lane>>4)*4 + reg; bf16 out
  const int ccol = lane & 15;
  const int crow = (lane >> 4) * 4;
  float bv[4];
#pragma unroll
  for (int j = 0; j < 4; j++) bv[j] = bias[n0 + tn + j * 16 + ccol];
#pragma unroll
  for (int i = 0; i < 4; i++) {
#pragma unroll
    for (int j = 0; j < 4; j++) {
      const size_t base =
          (size_t)(m0 + tm + i * 16 + crow) * N + (n0 + tn + j * 16 + ccol);
#pragma unroll
      for (int r = 0; r < 4; r++)
        C[base + (size_t)r * N] = (__bf16)(acc[i][j][r] + bv[j]);
    }
  }
}

// ---------------------------------------------------------------------------
// IndRNN scan, LDS-pipelined: one single-wave block per 64 chains. Input
// tiles (64 t x 64 chains, 8 KB bf16) stream in via global_load_lds into a
// double buffer -- no registers on the load path, so no spill risk and the
// prefetch for tile k+1 is in flight while tile k is consumed. Per step:
// ds_read_u16 (2-way bank alias = free) + fma/max + direct coalesced store.
// ---------------------------------------------------------------------------
#define TS 64
template <bool BF16OUT>
__global__ __launch_bounds__(64, 1) void scan_kernel(
    const __bf16* __restrict__ pre, // [T, BH] bf16
    const float* __restrict__ h0,   // [BH]
    const float* __restrict__ u,    // [H]
    void* __restrict__ outp,        // [T, BH] bf16 or f32
    float* __restrict__ hn) {       // [BH]
  __shared__ __bf16 tin[2][TS * 64]; // 2 x 8 KB

  const int lane = threadIdx.x;
  const int c0 = blockIdx.x * 64;
  const int idx = c0 + lane;
  const float uu = u[idx & (H_DIM - 1)];
  float h = h0[idx];
  __bf16* __restrict__ ob = (__bf16*)outp;
  float* __restrict__ of = (float*)outp;

  const int lrow = lane >> 3;        // 0..7
  const int lcg = (lane & 7) * 8;    // chain sub-offset (16 B unit)

  // prefetch tile 0 into buffer 0
#pragma unroll
  for (int i = 0; i < 8; i++)
    async_load16(&pre[(size_t)(i * 8 + lrow) * BH + c0 + lcg], &tin[0][i * 512]);

  const int NT = T_DIM / TS; // 16 tiles
  for (int tile = 0; tile < NT; tile++) {
    const int buf = tile & 1;
    const int t0 = tile * TS;
    // prefetch tile+1 into the other buffer (issued before the drain so it
    // lands during this tile's compute window on the co-resident wave)
    if (tile + 1 < NT) {
      const int nt0 = (tile + 1) * TS;
#pragma unroll
      for (int i = 0; i < 8; i++)
        async_load16(&pre[(size_t)(nt0 + i * 8 + lrow) * BH + c0 + lcg],
                     &tin[buf ^ 1][i * 512]);
    }
    __syncthreads(); // drains vmcnt -> tin[buf] (and the new prefetch) ready
#pragma unroll
    for (int s = 0; s < TS; s++) {
      const float p = (float)tin[buf][s * 64 + lane];
      h = fmaxf(fmaf(uu, h, p), 0.0f);
      if (BF16OUT)
        ob[(size_t)(t0 + s) * BH + idx] = (__bf16)h;
      else
        of[(size_t)(t0 + s) * BH + idx] = h;
    }
    __syncthreads(); // protect tin[buf] before it is re-filled next round
  }
  hn[idx] = h;
}

// ---------------------------------------------------------------------------
extern "C" void kernel_launch(void* const* d_in, const int* in_sizes, int n_in,
                              void* d_out, int out_size, void* d_ws,
                              size_t ws_size, hipStream_t stream) {
  (void)in_sizes; (void)n_in; (void)out_size; (void)ws_size;
  const float* x      = (const float*)d_in[0]; // [T,B,D]
  const float* hidden = (const float*)d_in[1]; // [L,B,H]
  const float* fc_w   = (const float*)d_in[2]; // [D,D]
  const float* fc_b   = (const float*)d_in[3]; // [D]
  const float* w0     = (const float*)d_in[4]; // [H,D]
  const float* b0     = (const float*)d_in[5]; // [H]
  const float* u0     = (const float*)d_in[6]; // [H]
  const float* w1     = (const float*)d_in[7]; // [H,H]
  const float* b1     = (const float*)d_in[8]; // [H]
  const float* u1     = (const float*)d_in[9]; // [H]
  float* out = (float*)d_out;

  // workspace (~192 MB): xbf / pre / out0 (bf16, 64 MB each) + small weights
  char* ws = (char*)d_ws;
  __bf16* xbf  = (__bf16*)ws;                   // 64 MB
  __bf16* pre  = (__bf16*)(ws + TBH * 2);       // 64 MB (pre0, then pre1)
  __bf16* out0 = (__bf16*)(ws + 2 * TBH * 2);   // 64 MB
  char*   tail = ws + 3 * TBH * 2;
  __bf16* Wc    = (__bf16*)tail;                // 512 KB
  __bf16* w1bf  = (__bf16*)(tail + 512 * 1024); // 512 KB
  float*  bcomb = (float*)(tail + 1024 * 1024); // 2 KB

  float* hn = out + TBH; // [2, BH] after out1

  // 1) prep: Wc = w0@fc_w (bf16), w1->bf16, bcomb = b0 + w0@fc_b
  prep_kernel<<<1154, 256, 0, stream>>>(w0, fc_w, fc_b, b0, w1, Wc, w1bf, bcomb);
  // 2) x -> bf16 (streaming, reads x exactly once)
  cvt_bf16_kernel<<<(int)(TBH / (256 * 8)), 256, 0, stream>>>(x, xbf, (long)TBH);
  // 3) pre0 = xbf @ Wc^T + bcomb -> bf16
  gemm_bt_bias<<<(TBROWS / BM) * (H_DIM / BN), 256, 0, stream>>>(
      xbf, Wc, bcomb, pre, TBROWS, H_DIM, D_DIM);
  // 4) layer-0 scan: out0 (bf16), hn[0]
  scan_kernel<true><<<BH / 64, 64, 0, stream>>>(pre, hidden, u0, (void*)out0, hn);
  // 5) pre1 = out0 @ w1^T + b1 -> bf16 (reuse pre buffer)
  gemm_bt_bias<<<(TBROWS / BM) * (H_DIM / BN), 256, 0, stream>>>(
      out0, w1bf, b1, pre, TBROWS, H_DIM, H_DIM);
  // 6) layer-1 scan: out1 (f32) -> d_out, hn[1]
  scan_kernel<false><<<BH / 64, 64, 0, stream>>>(pre, hidden + BH, u1,
                                                 (void*)out, hn + BH);
}